// Round 10
// baseline (557.548 us; speedup 1.0000x reference)
//
#include <hip/hip_runtime.h>
#include <math.h>

namespace {

constexpr int Bdim  = 4096;
constexpr int D_IN  = 2048;
constexpr int D_CTX = 512;
constexpr int UNITS = 2048;
constexpr int RANK  = 256;
constexpr int SPLIT = 4;

typedef __bf16 bf16x8 __attribute__((ext_vector_type(8)));
typedef float  f32x4  __attribute__((ext_vector_type(4)));

// ---------------------------------------------------------------------------
// Prep: Ut[256][2048] = bf16(U^T), Wt[256][512] = bf16(W^T)
// ---------------------------------------------------------------------------
__global__ __launch_bounds__(256) void k_prep(
    const float* __restrict__ U, const float* __restrict__ W,
    __bf16* __restrict__ Ut, __bf16* __restrict__ Wt) {
  const int job = blockIdx.y;
  const int t = threadIdx.x;
  const float* src = job ? W : U;
  __bf16* dst      = job ? Wt : Ut;
  const int K = job ? D_CTX : D_IN;   // rows of src
  const int tilesK = K / 64;
  const int tid = blockIdx.x;
  if (tid >= tilesK * 4) return;      // N=256 -> 4 col tiles
  const int k0 = (tid % tilesK) * 64;
  const int n0 = (tid / tilesK) * 64;
  __shared__ __bf16 T[64][72];        // [n][k], pitch 144B (16B-aligned)
  const int i  = t >> 4;              // src row in tile (step 16)
  const int j4 = (t & 15) * 4;        // src col
  for (int ii = i; ii < 64; ii += 16) {
    float4 v = *(const float4*)(src + (size_t)(k0 + ii) * RANK + n0 + j4);
    T[j4 + 0][ii] = (__bf16)v.x;
    T[j4 + 1][ii] = (__bf16)v.y;
    T[j4 + 2][ii] = (__bf16)v.z;
    T[j4 + 3][ii] = (__bf16)v.w;
  }
  __syncthreads();
  const int jj = t >> 3;              // out row in tile (step 32)
  const int c  = t & 7;               // 16B chunk
  for (int j2 = jj; j2 < 64; j2 += 32) {
    bf16x8 v = *(const bf16x8*)&T[j2][c * 8];
    *(bf16x8*)(dst + (size_t)(n0 + j2) * K + k0 + c * 8) = v;
  }
}

// ---------------------------------------------------------------------------
// Merged gate + split-K partial kernel.  BM=32, BN=128, BK=64, 2x2 waves.
//   blockIdx.y 0..1   : gate n-half -> s = bf16(S*sigmoid(ctx@Wt^T+Bc)) K=512
//   blockIdx.y 2..9   : slice=(y-2)>>1, n-half=(y-2)&1 -> part[slice], Kc=512
// 2-DEEP register prefetch (load k+2 while computing k; ~960cy lead >= HBM
// latency) + LDS double buffer (one barrier per K-step). 1280 blocks.
// ---------------------------------------------------------------------------
__global__ __launch_bounds__(256) void k_pg(
    const float* __restrict__ x,   const __bf16* __restrict__ Ut,
    const float* __restrict__ ctx, const __bf16* __restrict__ Wt,
    const float* __restrict__ S,   const float* __restrict__ Bc,
    __bf16* __restrict__ part, __bf16* __restrict__ s_out) {
  constexpr int BM = 32, BN = 128, BK = 64;
  __shared__ __align__(16) __bf16 As[2][BM * BK];   // 2 x 4 KB
  __shared__ __align__(16) __bf16 Bs[2][BN * BK];   // 2 x 16 KB
  const int t = threadIdx.x;
  const int y = blockIdx.y;
  const bool gate = (y < 2);
  const int nh    = gate ? y : ((y - 2) & 1);
  const int slice = (y - 2) >> 1;
  const int bm = blockIdx.x * BM;
  const int bn = nh * BN;
  const float*  A = gate ? ctx : x;
  const __bf16* B = gate ? Wt  : Ut;
  const int Kt   = gate ? D_CTX : D_IN;
  const int k_lo = gate ? 0 : slice * (D_IN / SPLIT);
  const int k_hi = gate ? D_CTX : k_lo + (D_IN / SPLIT);
  const int w = t >> 6, l = t & 63;
  const int wr0 = (w >> 1) * 16;      // 2 waves over M
  const int wc0 = (w & 1) * 64;       // 2 waves over N
  const int lrow = l & 15;
  const int lk   = l >> 4;
  f32x4 acc[4] = {};                  // FM=1, FN=4

  // 2-deep register prefetch slots
  float4 a_lo[2], a_hi[2];
  bf16x8 b_bf[2][4];
  const int srow = t >> 3, skc = t & 7;   // A staging: 1 chunk/thread

  auto LOADA = [&](int sl, int k0) {
    const float* g = A + (size_t)(bm + srow) * Kt + k0 + skc * 8;
    a_lo[sl] = *(const float4*)g;
    a_hi[sl] = *(const float4*)(g + 4);
  };
  auto LOADB = [&](int sl, int k0) {
#pragma unroll
    for (int ci = 0; ci < 4; ++ci) {
      const int c = t + ci * 256;
      const int row = c >> 3, kc = c & 7;
      b_bf[sl][ci] = *(const bf16x8*)(B + (size_t)(bn + row) * Kt + k0 + kc * 8);
    }
  };
  auto WRITEA = [&](int buf, int sl) {
    bf16x8 v;
    v[0] = (__bf16)a_lo[sl].x; v[1] = (__bf16)a_lo[sl].y;
    v[2] = (__bf16)a_lo[sl].z; v[3] = (__bf16)a_lo[sl].w;
    v[4] = (__bf16)a_hi[sl].x; v[5] = (__bf16)a_hi[sl].y;
    v[6] = (__bf16)a_hi[sl].z; v[7] = (__bf16)a_hi[sl].w;
    *(bf16x8*)((char*)As[buf] + srow * 128 + ((skc ^ (srow & 7)) * 16)) = v;
  };
  auto WRITEB = [&](int buf, int sl) {
#pragma unroll
    for (int ci = 0; ci < 4; ++ci) {
      const int c = t + ci * 256;
      const int row = c >> 3, kc = c & 7;
      *(bf16x8*)((char*)Bs[buf] + row * 128 + ((kc ^ (row & 7)) * 16)) =
          b_bf[sl][ci];
    }
  };

  LOADA(0, k_lo);
  LOADB(0, k_lo);
  if (k_lo + BK < k_hi) {
    LOADA(1, k_lo + BK);
    LOADB(1, k_lo + BK);
  }
  int cur = 0, p = 0;
  for (int k0 = k_lo; k0 < k_hi; k0 += BK) {
    WRITEA(cur, p);                  // waits vmcnt on slot-p loads (2 steps old)
    WRITEB(cur, p);
    __syncthreads();                 // cur buffer ready for all waves
    if (k0 + 2 * BK < k_hi) {        // refill slot p with tile k+2
      LOADA(p, k0 + 2 * BK);
      LOADB(p, k0 + 2 * BK);
    }
#pragma unroll
    for (int kk = 0; kk < 2; ++kk) {
      bf16x8 af, bfr[4];
      {
        const int row = wr0 + lrow;
        af = *(const bf16x8*)((const char*)As[cur] + row * 128 +
                              (((kk * 4 + lk) ^ (row & 7)) * 16));
      }
#pragma unroll
      for (int nf = 0; nf < 4; ++nf) {
        const int row = wc0 + nf * 16 + lrow;
        bfr[nf] = *(const bf16x8*)((const char*)Bs[cur] + row * 128 +
                                   (((kk * 4 + lk) ^ (row & 7)) * 16));
      }
#pragma unroll
      for (int nf = 0; nf < 4; ++nf)
        acc[nf] = __builtin_amdgcn_mfma_f32_16x16x32_bf16(af, bfr[nf], acc[nf], 0, 0, 0);
    }
    cur ^= 1;                        // barrier above ordered prior reads
    p ^= 1;
  }

#pragma unroll
  for (int nf = 0; nf < 4; ++nf) {
#pragma unroll
    for (int r = 0; r < 4; ++r) {
      const int m = bm + wr0 + lk * 4 + r;
      const int n = bn + wc0 + nf * 16 + lrow;
      const float val = acc[nf][r];
      if (gate) {
        const float h = val + Bc[n];
        s_out[(size_t)m * RANK + n] = (__bf16)(S[n] / (1.0f + __expf(-h)));
      } else {
        part[((size_t)slice * Bdim + m) * RANK + n] = (__bf16)val;
      }
    }
  }
}

// ---------------------------------------------------------------------------
// Combine: proj = bf16( (sum_sl part[sl]) * s ), 8 elems/thread, 512 blocks
// ---------------------------------------------------------------------------
__global__ __launch_bounds__(256) void k_combine(
    const __bf16* __restrict__ part, const __bf16* __restrict__ s,
    __bf16* __restrict__ proj) {
  const size_t i8 = ((size_t)blockIdx.x * 256 + threadIdx.x) * 8;
  float sum[8] = {};
#pragma unroll
  for (int sl = 0; sl < SPLIT; ++sl) {
    bf16x8 v = *(const bf16x8*)(part + (size_t)sl * Bdim * RANK + i8);
#pragma unroll
    for (int i = 0; i < 8; ++i) sum[i] += (float)v[i];
  }
  bf16x8 sv = *(const bf16x8*)(s + i8);
  bf16x8 o;
#pragma unroll
  for (int i = 0; i < 8; ++i) o[i] = (__bf16)(sum[i] * (float)sv[i]);
  *(bf16x8*)(proj + i8) = o;
}

// ---------------------------------------------------------------------------
// Out: out[m][n] = proj[m][:] @ V[n][:] + bias[n].  BM=BN=128, 4 waves (2x2).
//   A = proj bf16 [4096][256]; B = V fp32 [2048][256] staged w/ convert.
//   XCD-aware bijective swizzle of the 512 tiles (64 consecutive per XCD).
// ---------------------------------------------------------------------------
__global__ __launch_bounds__(256) void k_out(
    const __bf16* __restrict__ proj, const float* __restrict__ V,
    const float* __restrict__ bias, float* __restrict__ out) {
  constexpr int BM = 128, BN = 128, BK = 64;
  constexpr int Kt = RANK;
  __shared__ __align__(16) __bf16 As[BM * BK];
  __shared__ __align__(16) __bf16 Bs[BN * BK];
  const int t = threadIdx.x;
  // swizzle: lin -> (lin%8)*64 + lin/8 ; grid (32,16) = 512 tiles, 64/XCD
  const int lin = (int)(blockIdx.y * gridDim.x + blockIdx.x);
  const int swz = (lin & 7) * 64 + (lin >> 3);
  const int bm = (swz & 31) * BM;   // 32 m-tiles
  const int bn = (swz >> 5) * BN;   // 16 n-tiles
  const int w = t >> 6, l = t & 63;
  const int wr0 = (w >> 1) * 64;    // 2x2 waves
  const int wc0 = (w & 1) * 64;
  const int lrow = l & 15;
  const int lk   = l >> 4;
  f32x4 acc[4][4] = {};

  bf16x8 a_bf[4];
  float4 b_lo[4], b_hi[4];

  auto LOADA = [&](int k0) {
#pragma unroll
    for (int ci = 0; ci < 4; ++ci) {
      const int c = t + ci * 256;
      const int row = c >> 3, kc = c & 7;
      a_bf[ci] = *(const bf16x8*)(proj + (size_t)(bm + row) * Kt + k0 + kc * 8);
    }
  };
  auto LOADB = [&](int k0) {
#pragma unroll
    for (int ci = 0; ci < 4; ++ci) {
      const int c = t + ci * 256;
      const int row = c >> 3, kc = c & 7;
      const float* g = V + (size_t)(bn + row) * Kt + k0 + kc * 8;
      b_lo[ci] = *(const float4*)g;
      b_hi[ci] = *(const float4*)(g + 4);
    }
  };
  auto WRITEA = [&]() {
#pragma unroll
    for (int ci = 0; ci < 4; ++ci) {
      const int c = t + ci * 256;
      const int row = c >> 3, kc = c & 7;
      *(bf16x8*)((char*)As + row * 128 + ((kc ^ (row & 7)) * 16)) = a_bf[ci];
    }
  };
  auto WRITEB = [&]() {
#pragma unroll
    for (int ci = 0; ci < 4; ++ci) {
      const int c = t + ci * 256;
      const int row = c >> 3, kc = c & 7;
      bf16x8 v;
      v[0] = (__bf16)b_lo[ci].x; v[1] = (__bf16)b_lo[ci].y;
      v[2] = (__bf16)b_lo[ci].z; v[3] = (__bf16)b_lo[ci].w;
      v[4] = (__bf16)b_hi[ci].x; v[5] = (__bf16)b_hi[ci].y;
      v[6] = (__bf16)b_hi[ci].z; v[7] = (__bf16)b_hi[ci].w;
      *(bf16x8*)((char*)Bs + row * 128 + ((kc ^ (row & 7)) * 16)) = v;
    }
  };

  LOADA(0);
  LOADB(0);
  for (int k0 = 0; k0 < Kt; k0 += BK) {
    WRITEA();
    WRITEB();
    __syncthreads();
    if (k0 + BK < Kt) {
      LOADA(k0 + BK);
      LOADB(k0 + BK);
    }
#pragma unroll
    for (int kk = 0; kk < 2; ++kk) {
      bf16x8 af[4], bfr[4];
#pragma unroll
      for (int mf = 0; mf < 4; ++mf) {
        const int row = wr0 + mf * 16 + lrow;
        af[mf] = *(const bf16x8*)((const char*)As + row * 128 +
                                  (((kk * 4 + lk) ^ (row & 7)) * 16));
      }
#pragma unroll
      for (int nf = 0; nf < 4; ++nf) {
        const int row = wc0 + nf * 16 + lrow;
        bfr[nf] = *(const bf16x8*)((const char*)Bs + row * 128 +
                                   (((kk * 4 + lk) ^ (row & 7)) * 16));
      }
#pragma unroll
      for (int mf = 0; mf < 4; ++mf)
#pragma unroll
        for (int nf = 0; nf < 4; ++nf)
          acc[mf][nf] = __builtin_amdgcn_mfma_f32_16x16x32_bf16(
              af[mf], bfr[nf], acc[mf][nf], 0, 0, 0);
    }
    __syncthreads();
  }

#pragma unroll
  for (int mf = 0; mf < 4; ++mf) {
#pragma unroll
    for (int nf = 0; nf < 4; ++nf) {
#pragma unroll
      for (int r = 0; r < 4; ++r) {
        const int m = bm + wr0 + mf * 16 + lk * 4 + r;
        const int n = bn + wc0 + nf * 16 + lrow;
        out[(size_t)m * UNITS + n] = acc[mf][nf][r] + bias[n];
      }
    }
  }
}

}  // namespace

extern "C" void kernel_launch(void* const* d_in, const int* in_sizes, int n_in,
                              void* d_out, int out_size, void* d_ws, size_t ws_size,
                              hipStream_t stream) {
  const float* inputs  = (const float*)d_in[0];  // [4096, 2048]
  const float* context = (const float*)d_in[1];  // [4096, 512]
  const float* U       = (const float*)d_in[2];  // [2048, 256]
  const float* S       = (const float*)d_in[3];  // [256]
  const float* V       = (const float*)d_in[4];  // [2048, 256]
  const float* W       = (const float*)d_in[5];  // [512, 256]
  const float* Bc      = (const float*)d_in[6];  // [256]
  const float* bias    = (const float*)d_in[7];  // [2048]
  float* out = (float*)d_out;                    // [4096, 2048]

  char* ws = (char*)d_ws;
  __bf16* Ut   = (__bf16*)(ws);                  // 256x2048         (1 MB)
  __bf16* Wt   = (__bf16*)(ws + 1048576);        // 256x512          (256 KB)
  __bf16* proj = (__bf16*)(ws + 1310720);        // 4096x256         (2 MB)
  __bf16* sbuf = (__bf16*)(ws + 3407872);        // 4096x256         (2 MB)
  __bf16* part = (__bf16*)(ws + 5505024);        // SPLIT x4096x256  (8 MB)

  // 1) weight transpose+convert (Ut, Wt)
  k_prep<<<dim3(128, 2), 256, 0, stream>>>(U, W, Ut, Wt);

  // 2) merged: gate (y=0..1, writes s) + xU split-K partials (y=2..9)
  k_pg<<<dim3(Bdim / 32, 2 * SPLIT + 2), 256, 0, stream>>>(
      inputs, Ut, context, Wt, S, Bc, part, sbuf);

  // 3) proj = bf16( (sum partials) * s )   — pure-BW elementwise
  k_combine<<<dim3((Bdim * RANK) / (256 * 8)), 256, 0, stream>>>(part, sbuf, proj);

  // 4) out = proj @ V^T + bias   (V staged from fp32, XCD-swizzled tiles)
  k_out<<<dim3(Bdim / 128, UNITS / 128), 256, 0, stream>>>(proj, V, bias, out);
}

// Round 11
// 44.142 us; speedup vs baseline: 12.6309x; 12.6309x over previous
//
#include <hip/hip_runtime.h>
#include <math.h>

namespace {

constexpr int Bdim  = 4096;
constexpr int D_IN  = 2048;
constexpr int D_CTX = 512;
constexpr int UNITS = 2048;
constexpr int RANK  = 256;
constexpr int SPLIT = 4;

typedef __bf16 bf16x8 __attribute__((ext_vector_type(8)));
typedef float  f32x4  __attribute__((ext_vector_type(4)));

// ---------------------------------------------------------------------------
// Prep: Ut[256][2048] = bf16(U^T), Wt[256][512] = bf16(W^T)
// ---------------------------------------------------------------------------
__global__ __launch_bounds__(256) void k_prep(
    const float* __restrict__ U, const float* __restrict__ W,
    __bf16* __restrict__ Ut, __bf16* __restrict__ Wt) {
  const int job = blockIdx.y;
  const int t = threadIdx.x;
  const float* src = job ? W : U;
  __bf16* dst      = job ? Wt : Ut;
  const int K = job ? D_CTX : D_IN;   // rows of src
  const int tilesK = K / 64;
  const int tid = blockIdx.x;
  if (tid >= tilesK * 4) return;      // N=256 -> 4 col tiles
  const int k0 = (tid % tilesK) * 64;
  const int n0 = (tid / tilesK) * 64;
  __shared__ __bf16 T[64][72];        // [n][k], pitch 144B (16B-aligned)
  const int i  = t >> 4;              // src row in tile (step 16)
  const int j4 = (t & 15) * 4;        // src col
  for (int ii = i; ii < 64; ii += 16) {
    float4 v = *(const float4*)(src + (size_t)(k0 + ii) * RANK + n0 + j4);
    T[j4 + 0][ii] = (__bf16)v.x;
    T[j4 + 1][ii] = (__bf16)v.y;
    T[j4 + 2][ii] = (__bf16)v.z;
    T[j4 + 3][ii] = (__bf16)v.w;
  }
  __syncthreads();
  const int jj = t >> 3;              // out row in tile (step 32)
  const int c  = t & 7;               // 16B chunk
  for (int j2 = jj; j2 < 64; j2 += 32) {
    bf16x8 v = *(const bf16x8*)&T[j2][c * 8];
    *(bf16x8*)(dst + (size_t)(n0 + j2) * K + k0 + c * 8) = v;
  }
}

// ---------------------------------------------------------------------------
// Merged gate + split-K partial kernel.  BM=32, BN=128, BK=64, 2x2 waves.
//   blockIdx.y 0..1   : gate n-half -> s = bf16(S*sigmoid(ctx@Wt^T+Bc)) K=512
//   blockIdx.y 2..9   : slice=(y-2)>>1, n-half=(y-2)&1 -> part[slice], Kc=512
// 2-deep register prefetch with STATIC slot names (rule #20: no runtime
// indexing of register arrays) + LDS double buffer, 2x-unrolled loop (both
// paths have 8 K-steps — even, no tail). One barrier per K-step.
// ---------------------------------------------------------------------------
__global__ __launch_bounds__(256) void k_pg(
    const float* __restrict__ x,   const __bf16* __restrict__ Ut,
    const float* __restrict__ ctx, const __bf16* __restrict__ Wt,
    const float* __restrict__ S,   const float* __restrict__ Bc,
    __bf16* __restrict__ part, __bf16* __restrict__ s_out) {
  constexpr int BM = 32, BN = 128, BK = 64;
  __shared__ __align__(16) __bf16 As[2][BM * BK];   // 2 x 4 KB
  __shared__ __align__(16) __bf16 Bs[2][BN * BK];   // 2 x 16 KB
  const int t = threadIdx.x;
  const int y = blockIdx.y;
  const bool gate = (y < 2);
  const int nh    = gate ? y : ((y - 2) & 1);
  const int slice = (y - 2) >> 1;
  const int bm = blockIdx.x * BM;
  const int bn = nh * BN;
  const float*  A = gate ? ctx : x;
  const __bf16* B = gate ? Wt  : Ut;
  const int Kt   = gate ? D_CTX : D_IN;
  const int k_lo = gate ? 0 : slice * (D_IN / SPLIT);
  const int k_hi = gate ? D_CTX : k_lo + (D_IN / SPLIT);
  const int w = t >> 6, l = t & 63;
  const int wr0 = (w >> 1) * 16;      // 2 waves over M
  const int wc0 = (w & 1) * 64;       // 2 waves over N
  const int lrow = l & 15;
  const int lk   = l >> 4;
  f32x4 acc[4] = {};                  // FM=1, FN=4

  // two STATICALLY-NAMED prefetch slots
  float4 a0_lo, a0_hi, a1_lo, a1_hi;
  bf16x8 b0[4], b1[4];
  const int srow = t >> 3, skc = t & 7;   // A staging: 1 chunk/thread

  auto LOADA = [&](float4& lo, float4& hi, int k0) {
    const float* g = A + (size_t)(bm + srow) * Kt + k0 + skc * 8;
    lo = *(const float4*)g;
    hi = *(const float4*)(g + 4);
  };
  auto LOADB = [&](bf16x8 (&bb)[4], int k0) {
#pragma unroll
    for (int ci = 0; ci < 4; ++ci) {
      const int c = t + ci * 256;
      const int row = c >> 3, kc = c & 7;
      bb[ci] = *(const bf16x8*)(B + (size_t)(bn + row) * Kt + k0 + kc * 8);
    }
  };
  auto WRITEA = [&](char* dstAs, const float4& lo, const float4& hi) {
    bf16x8 v;
    v[0] = (__bf16)lo.x; v[1] = (__bf16)lo.y;
    v[2] = (__bf16)lo.z; v[3] = (__bf16)lo.w;
    v[4] = (__bf16)hi.x; v[5] = (__bf16)hi.y;
    v[6] = (__bf16)hi.z; v[7] = (__bf16)hi.w;
    *(bf16x8*)(dstAs + srow * 128 + ((skc ^ (srow & 7)) * 16)) = v;
  };
  auto WRITEB = [&](char* dstBs, const bf16x8 (&bb)[4]) {
#pragma unroll
    for (int ci = 0; ci < 4; ++ci) {
      const int c = t + ci * 256;
      const int row = c >> 3, kc = c & 7;
      *(bf16x8*)(dstBs + row * 128 + ((kc ^ (row & 7)) * 16)) = bb[ci];
    }
  };
  auto MFMA_STEP = [&](const char* curAs, const char* curBs) {
#pragma unroll
    for (int kk = 0; kk < 2; ++kk) {
      bf16x8 af, bfr[4];
      {
        const int row = wr0 + lrow;
        af = *(const bf16x8*)(curAs + row * 128 +
                              (((kk * 4 + lk) ^ (row & 7)) * 16));
      }
#pragma unroll
      for (int nf = 0; nf < 4; ++nf) {
        const int row = wc0 + nf * 16 + lrow;
        bfr[nf] = *(const bf16x8*)(curBs + row * 128 +
                                   (((kk * 4 + lk) ^ (row & 7)) * 16));
      }
#pragma unroll
      for (int nf = 0; nf < 4; ++nf)
        acc[nf] = __builtin_amdgcn_mfma_f32_16x16x32_bf16(af, bfr[nf], acc[nf], 0, 0, 0);
    }
  };

  LOADA(a0_lo, a0_hi, k_lo);
  LOADB(b0, k_lo);
  LOADA(a1_lo, a1_hi, k_lo + BK);
  LOADB(b1, k_lo + BK);
  for (int k0 = k_lo; k0 < k_hi; k0 += 2 * BK) {
    // ---- step 0: LDS buf 0 <- slot 0
    WRITEA((char*)As[0], a0_lo, a0_hi);
    WRITEB((char*)Bs[0], b0);
    __syncthreads();
    if (k0 + 2 * BK < k_hi) {        // refill slot 0 with tile k+2
      LOADA(a0_lo, a0_hi, k0 + 2 * BK);
      LOADB(b0, k0 + 2 * BK);
    }
    MFMA_STEP((const char*)As[0], (const char*)Bs[0]);
    // ---- step 1: LDS buf 1 <- slot 1
    WRITEA((char*)As[1], a1_lo, a1_hi);
    WRITEB((char*)Bs[1], b1);
    __syncthreads();
    if (k0 + 3 * BK < k_hi) {        // refill slot 1 with tile k+3
      LOADA(a1_lo, a1_hi, k0 + 3 * BK);
      LOADB(b1, k0 + 3 * BK);
    }
    MFMA_STEP((const char*)As[1], (const char*)Bs[1]);
  }

#pragma unroll
  for (int nf = 0; nf < 4; ++nf) {
#pragma unroll
    for (int r = 0; r < 4; ++r) {
      const int m = bm + wr0 + lk * 4 + r;
      const int n = bn + wc0 + nf * 16 + lrow;
      const float val = acc[nf][r];
      if (gate) {
        const float h = val + Bc[n];
        s_out[(size_t)m * RANK + n] = (__bf16)(S[n] / (1.0f + __expf(-h)));
      } else {
        part[((size_t)slice * Bdim + m) * RANK + n] = (__bf16)val;
      }
    }
  }
}

// ---------------------------------------------------------------------------
// Combine: proj = bf16( (sum_sl part[sl]) * s ), 8 elems/thread, 512 blocks
// ---------------------------------------------------------------------------
__global__ __launch_bounds__(256) void k_combine(
    const __bf16* __restrict__ part, const __bf16* __restrict__ s,
    __bf16* __restrict__ proj) {
  const size_t i8 = ((size_t)blockIdx.x * 256 + threadIdx.x) * 8;
  float sum[8] = {};
#pragma unroll
  for (int sl = 0; sl < SPLIT; ++sl) {
    bf16x8 v = *(const bf16x8*)(part + (size_t)sl * Bdim * RANK + i8);
#pragma unroll
    for (int i = 0; i < 8; ++i) sum[i] += (float)v[i];
  }
  bf16x8 sv = *(const bf16x8*)(s + i8);
  bf16x8 o;
#pragma unroll
  for (int i = 0; i < 8; ++i) o[i] = (__bf16)(sum[i] * (float)sv[i]);
  *(bf16x8*)(proj + i8) = o;
}

// ---------------------------------------------------------------------------
// Out: out[m][n] = proj[m][:] @ V[n][:] + bias[n].  BM=BN=128, 4 waves (2x2).
//   A = proj bf16 [4096][256]; B = V fp32 [2048][256] staged w/ convert.
//   XCD-aware bijective swizzle of the 512 tiles (64 consecutive per XCD).
// ---------------------------------------------------------------------------
__global__ __launch_bounds__(256) void k_out(
    const __bf16* __restrict__ proj, const float* __restrict__ V,
    const float* __restrict__ bias, float* __restrict__ out) {
  constexpr int BM = 128, BN = 128, BK = 64;
  constexpr int Kt = RANK;
  __shared__ __align__(16) __bf16 As[BM * BK];
  __shared__ __align__(16) __bf16 Bs[BN * BK];
  const int t = threadIdx.x;
  // swizzle: lin -> (lin%8)*64 + lin/8 ; grid (32,16) = 512 tiles, 64/XCD
  const int lin = (int)(blockIdx.y * gridDim.x + blockIdx.x);
  const int swz = (lin & 7) * 64 + (lin >> 3);
  const int bm = (swz & 31) * BM;   // 32 m-tiles
  const int bn = (swz >> 5) * BN;   // 16 n-tiles
  const int w = t >> 6, l = t & 63;
  const int wr0 = (w >> 1) * 64;    // 2x2 waves
  const int wc0 = (w & 1) * 64;
  const int lrow = l & 15;
  const int lk   = l >> 4;
  f32x4 acc[4][4] = {};

  bf16x8 a_bf[4];
  float4 b_lo[4], b_hi[4];

  auto LOADA = [&](int k0) {
#pragma unroll
    for (int ci = 0; ci < 4; ++ci) {
      const int c = t + ci * 256;
      const int row = c >> 3, kc = c & 7;
      a_bf[ci] = *(const bf16x8*)(proj + (size_t)(bm + row) * Kt + k0 + kc * 8);
    }
  };
  auto LOADB = [&](int k0) {
#pragma unroll
    for (int ci = 0; ci < 4; ++ci) {
      const int c = t + ci * 256;
      const int row = c >> 3, kc = c & 7;
      const float* g = V + (size_t)(bn + row) * Kt + k0 + kc * 8;
      b_lo[ci] = *(const float4*)g;
      b_hi[ci] = *(const float4*)(g + 4);
    }
  };
  auto WRITEA = [&]() {
#pragma unroll
    for (int ci = 0; ci < 4; ++ci) {
      const int c = t + ci * 256;
      const int row = c >> 3, kc = c & 7;
      *(bf16x8*)((char*)As + row * 128 + ((kc ^ (row & 7)) * 16)) = a_bf[ci];
    }
  };
  auto WRITEB = [&]() {
#pragma unroll
    for (int ci = 0; ci < 4; ++ci) {
      const int c = t + ci * 256;
      const int row = c >> 3, kc = c & 7;
      bf16x8 v;
      v[0] = (__bf16)b_lo[ci].x; v[1] = (__bf16)b_lo[ci].y;
      v[2] = (__bf16)b_lo[ci].z; v[3] = (__bf16)b_lo[ci].w;
      v[4] = (__bf16)b_hi[ci].x; v[5] = (__bf16)b_hi[ci].y;
      v[6] = (__bf16)b_hi[ci].z; v[7] = (__bf16)b_hi[ci].w;
      *(bf16x8*)((char*)Bs + row * 128 + ((kc ^ (row & 7)) * 16)) = v;
    }
  };

  LOADA(0);
  LOADB(0);
  for (int k0 = 0; k0 < Kt; k0 += BK) {
    WRITEA();
    WRITEB();
    __syncthreads();
    if (k0 + BK < Kt) {
      LOADA(k0 + BK);
      LOADB(k0 + BK);
    }
#pragma unroll
    for (int kk = 0; kk < 2; ++kk) {
      bf16x8 af[4], bfr[4];
#pragma unroll
      for (int mf = 0; mf < 4; ++mf) {
        const int row = wr0 + mf * 16 + lrow;
        af[mf] = *(const bf16x8*)((const char*)As + row * 128 +
                                  (((kk * 4 + lk) ^ (row & 7)) * 16));
      }
#pragma unroll
      for (int nf = 0; nf < 4; ++nf) {
        const int row = wc0 + nf * 16 + lrow;
        bfr[nf] = *(const bf16x8*)((const char*)Bs + row * 128 +
                                   (((kk * 4 + lk) ^ (row & 7)) * 16));
      }
#pragma unroll
      for (int mf = 0; mf < 4; ++mf)
#pragma unroll
        for (int nf = 0; nf < 4; ++nf)
          acc[mf][nf] = __builtin_amdgcn_mfma_f32_16x16x32_bf16(
              af[mf], bfr[nf], acc[mf][nf], 0, 0, 0);
    }
    __syncthreads();
  }

#pragma unroll
  for (int mf = 0; mf < 4; ++mf) {
#pragma unroll
    for (int nf = 0; nf < 4; ++nf) {
#pragma unroll
      for (int r = 0; r < 4; ++r) {
        const int m = bm + wr0 + mf * 16 + lk * 4 + r;
        const int n = bn + wc0 + nf * 16 + lrow;
        out[(size_t)m * UNITS + n] = acc[mf][nf][r] + bias[n];
      }
    }
  }
}

}  // namespace

extern "C" void kernel_launch(void* const* d_in, const int* in_sizes, int n_in,
                              void* d_out, int out_size, void* d_ws, size_t ws_size,
                              hipStream_t stream) {
  const float* inputs  = (const float*)d_in[0];  // [4096, 2048]
  const float* context = (const float*)d_in[1];  // [4096, 512]
  const float* U       = (const float*)d_in[2];  // [2048, 256]
  const float* S       = (const float*)d_in[3];  // [256]
  const float* V       = (const float*)d_in[4];  // [2048, 256]
  const float* W       = (const float*)d_in[5];  // [512, 256]
  const float* Bc      = (const float*)d_in[6];  // [256]
  const float* bias    = (const float*)d_in[7];  // [2048]
  float* out = (float*)d_out;                    // [4096, 2048]

  char* ws = (char*)d_ws;
  __bf16* Ut   = (__bf16*)(ws);                  // 256x2048         (1 MB)
  __bf16* Wt   = (__bf16*)(ws + 1048576);        // 256x512          (256 KB)
  __bf16* proj = (__bf16*)(ws + 1310720);        // 4096x256         (2 MB)
  __bf16* sbuf = (__bf16*)(ws + 3407872);        // 4096x256         (2 MB)
  __bf16* part = (__bf16*)(ws + 5505024);        // SPLIT x4096x256  (8 MB)

  // 1) weight transpose+convert (Ut, Wt)
  k_prep<<<dim3(128, 2), 256, 0, stream>>>(U, W, Ut, Wt);

  // 2) merged: gate (y=0..1, writes s) + xU split-K partials (y=2..9)
  k_pg<<<dim3(Bdim / 32, 2 * SPLIT + 2), 256, 0, stream>>>(
      inputs, Ut, context, Wt, S, Bc, part, sbuf);

  // 3) proj = bf16( (sum partials) * s )   — pure-BW elementwise
  k_combine<<<dim3((Bdim * RANK) / (256 * 8)), 256, 0, stream>>>(part, sbuf, proj);

  // 4) out = proj @ V^T + bias   (V staged from fp32, XCD-swizzled tiles)
  k_out<<<dim3(Bdim / 128, UNITS / 128), 256, 0, stream>>>(proj, V, bias, out);
}

// Round 12
// 43.476 us; speedup vs baseline: 12.8242x; 1.0153x over previous
//
#include <hip/hip_runtime.h>
#include <math.h>

namespace {

constexpr int Bdim  = 4096;
constexpr int D_IN  = 2048;
constexpr int D_CTX = 512;
constexpr int UNITS = 2048;
constexpr int RANK  = 256;
constexpr int SPLIT = 4;

typedef __bf16 bf16x8 __attribute__((ext_vector_type(8)));
typedef float  f32x4  __attribute__((ext_vector_type(4)));

// ---------------------------------------------------------------------------
// Prep: Ut[256][2048] = bf16(U^T), Wt[256][512] = bf16(W^T)
// ---------------------------------------------------------------------------
__global__ __launch_bounds__(256) void k_prep(
    const float* __restrict__ U, const float* __restrict__ W,
    __bf16* __restrict__ Ut, __bf16* __restrict__ Wt) {
  const int job = blockIdx.y;
  const int t = threadIdx.x;
  const float* src = job ? W : U;
  __bf16* dst      = job ? Wt : Ut;
  const int K = job ? D_CTX : D_IN;   // rows of src
  const int tilesK = K / 64;
  const int tid = blockIdx.x;
  if (tid >= tilesK * 4) return;      // N=256 -> 4 col tiles
  const int k0 = (tid % tilesK) * 64;
  const int n0 = (tid / tilesK) * 64;
  __shared__ __bf16 T[64][72];        // [n][k], pitch 144B (16B-aligned)
  const int i  = t >> 4;              // src row in tile (step 16)
  const int j4 = (t & 15) * 4;        // src col
  for (int ii = i; ii < 64; ii += 16) {
    float4 v = *(const float4*)(src + (size_t)(k0 + ii) * RANK + n0 + j4);
    T[j4 + 0][ii] = (__bf16)v.x;
    T[j4 + 1][ii] = (__bf16)v.y;
    T[j4 + 2][ii] = (__bf16)v.z;
    T[j4 + 3][ii] = (__bf16)v.w;
  }
  __syncthreads();
  const int jj = t >> 3;              // out row in tile (step 32)
  const int c  = t & 7;               // 16B chunk
  for (int j2 = jj; j2 < 64; j2 += 32) {
    bf16x8 v = *(const bf16x8*)&T[j2][c * 8];
    *(bf16x8*)(dst + (size_t)(n0 + j2) * K + k0 + c * 8) = v;
  }
}

// ---------------------------------------------------------------------------
// Merged gate + split-K partial kernel.  BM=64, BN=128, BK=64, 2x2 waves.
//   blockIdx.y 0..1   : gate n-half -> s = bf16(S*sigmoid(ctx@Wt^T+Bc)) K=512
//   blockIdx.y 2..9   : slice=(y-2)>>1, n-half=(y-2)&1 -> part[slice], Kc=512
// 640 blocks, 48KB LDS -> 3 blocks/CU, 768 capacity: WHOLE GRID CO-RESIDENT
// (no straggler tail). 2-deep static-named register prefetch + LDS dbuf,
// 2x-unrolled loop (8 K-steps both paths — even, no tail). 16 MFMA/step.
// ---------------------------------------------------------------------------
__global__ __launch_bounds__(256) void k_pg(
    const float* __restrict__ x,   const __bf16* __restrict__ Ut,
    const float* __restrict__ ctx, const __bf16* __restrict__ Wt,
    const float* __restrict__ S,   const float* __restrict__ Bc,
    __bf16* __restrict__ part, __bf16* __restrict__ s_out) {
  constexpr int BM = 64, BN = 128, BK = 64;
  __shared__ __align__(16) __bf16 As[2][BM * BK];   // 2 x 8 KB
  __shared__ __align__(16) __bf16 Bs[2][BN * BK];   // 2 x 16 KB
  const int t = threadIdx.x;
  const int y = blockIdx.y;
  const bool gate = (y < 2);
  const int nh    = gate ? y : ((y - 2) & 1);
  const int slice = (y - 2) >> 1;
  const int bm = blockIdx.x * BM;
  const int bn = nh * BN;
  const float*  A = gate ? ctx : x;
  const __bf16* B = gate ? Wt  : Ut;
  const int Kt   = gate ? D_CTX : D_IN;
  const int k_lo = gate ? 0 : slice * (D_IN / SPLIT);
  const int k_hi = gate ? D_CTX : k_lo + (D_IN / SPLIT);
  const int w = t >> 6, l = t & 63;
  const int wr0 = (w >> 1) * 32;      // 2 waves over M (32 rows each)
  const int wc0 = (w & 1) * 64;       // 2 waves over N
  const int lrow = l & 15;
  const int lk   = l >> 4;
  f32x4 acc[2][4] = {};               // FM=2, FN=4

  // two STATICALLY-NAMED prefetch slots (rule #20)
  float4 a0_lo[2], a0_hi[2], a1_lo[2], a1_hi[2];
  bf16x8 b0[4], b1[4];

  auto LOADA = [&](float4 (&lo)[2], float4 (&hi)[2], int k0) {
#pragma unroll
    for (int ci = 0; ci < 2; ++ci) {
      const int c = t + ci * 256;     // 512 chunks: row=c>>3, kc=c&7
      const int row = c >> 3, kc = c & 7;
      const float* g = A + (size_t)(bm + row) * Kt + k0 + kc * 8;
      lo[ci] = *(const float4*)g;
      hi[ci] = *(const float4*)(g + 4);
    }
  };
  auto LOADB = [&](bf16x8 (&bb)[4], int k0) {
#pragma unroll
    for (int ci = 0; ci < 4; ++ci) {
      const int c = t + ci * 256;
      const int row = c >> 3, kc = c & 7;
      bb[ci] = *(const bf16x8*)(B + (size_t)(bn + row) * Kt + k0 + kc * 8);
    }
  };
  auto WRITEA = [&](char* dstAs, const float4 (&lo)[2], const float4 (&hi)[2]) {
#pragma unroll
    for (int ci = 0; ci < 2; ++ci) {
      const int c = t + ci * 256;
      const int row = c >> 3, kc = c & 7;
      bf16x8 v;
      v[0] = (__bf16)lo[ci].x; v[1] = (__bf16)lo[ci].y;
      v[2] = (__bf16)lo[ci].z; v[3] = (__bf16)lo[ci].w;
      v[4] = (__bf16)hi[ci].x; v[5] = (__bf16)hi[ci].y;
      v[6] = (__bf16)hi[ci].z; v[7] = (__bf16)hi[ci].w;
      *(bf16x8*)(dstAs + row * 128 + ((kc ^ (row & 7)) * 16)) = v;
    }
  };
  auto WRITEB = [&](char* dstBs, const bf16x8 (&bb)[4]) {
#pragma unroll
    for (int ci = 0; ci < 4; ++ci) {
      const int c = t + ci * 256;
      const int row = c >> 3, kc = c & 7;
      *(bf16x8*)(dstBs + row * 128 + ((kc ^ (row & 7)) * 16)) = bb[ci];
    }
  };
  auto MFMA_STEP = [&](const char* curAs, const char* curBs) {
#pragma unroll
    for (int kk = 0; kk < 2; ++kk) {
      bf16x8 af[2], bfr[4];
#pragma unroll
      for (int mf = 0; mf < 2; ++mf) {
        const int row = wr0 + mf * 16 + lrow;
        af[mf] = *(const bf16x8*)(curAs + row * 128 +
                                  (((kk * 4 + lk) ^ (row & 7)) * 16));
      }
#pragma unroll
      for (int nf = 0; nf < 4; ++nf) {
        const int row = wc0 + nf * 16 + lrow;
        bfr[nf] = *(const bf16x8*)(curBs + row * 128 +
                                   (((kk * 4 + lk) ^ (row & 7)) * 16));
      }
#pragma unroll
      for (int mf = 0; mf < 2; ++mf)
#pragma unroll
        for (int nf = 0; nf < 4; ++nf)
          acc[mf][nf] = __builtin_amdgcn_mfma_f32_16x16x32_bf16(
              af[mf], bfr[nf], acc[mf][nf], 0, 0, 0);
    }
  };

  LOADA(a0_lo, a0_hi, k_lo);
  LOADB(b0, k_lo);
  LOADA(a1_lo, a1_hi, k_lo + BK);
  LOADB(b1, k_lo + BK);
  for (int k0 = k_lo; k0 < k_hi; k0 += 2 * BK) {
    // ---- step 0: LDS buf 0 <- slot 0
    WRITEA((char*)As[0], a0_lo, a0_hi);
    WRITEB((char*)Bs[0], b0);
    __syncthreads();
    if (k0 + 2 * BK < k_hi) {        // refill slot 0 with tile k+2
      LOADA(a0_lo, a0_hi, k0 + 2 * BK);
      LOADB(b0, k0 + 2 * BK);
    }
    MFMA_STEP((const char*)As[0], (const char*)Bs[0]);
    // ---- step 1: LDS buf 1 <- slot 1
    WRITEA((char*)As[1], a1_lo, a1_hi);
    WRITEB((char*)Bs[1], b1);
    __syncthreads();
    if (k0 + 3 * BK < k_hi) {        // refill slot 1 with tile k+3
      LOADA(a1_lo, a1_hi, k0 + 3 * BK);
      LOADB(b1, k0 + 3 * BK);
    }
    MFMA_STEP((const char*)As[1], (const char*)Bs[1]);
  }

#pragma unroll
  for (int mf = 0; mf < 2; ++mf) {
#pragma unroll
    for (int nf = 0; nf < 4; ++nf) {
#pragma unroll
      for (int r = 0; r < 4; ++r) {
        const int m = bm + wr0 + mf * 16 + lk * 4 + r;
        const int n = bn + wc0 + nf * 16 + lrow;
        const float val = acc[mf][nf][r];
        if (gate) {
          const float h = val + Bc[n];
          s_out[(size_t)m * RANK + n] = (__bf16)(S[n] / (1.0f + __expf(-h)));
        } else {
          part[((size_t)slice * Bdim + m) * RANK + n] = (__bf16)val;
        }
      }
    }
  }
}

// ---------------------------------------------------------------------------
// Combine: proj = bf16( (sum_sl part[sl]) * s ), 8 elems/thread, 512 blocks
// ---------------------------------------------------------------------------
__global__ __launch_bounds__(256) void k_combine(
    const __bf16* __restrict__ part, const __bf16* __restrict__ s,
    __bf16* __restrict__ proj) {
  const size_t i8 = ((size_t)blockIdx.x * 256 + threadIdx.x) * 8;
  float sum[8] = {};
#pragma unroll
  for (int sl = 0; sl < SPLIT; ++sl) {
    bf16x8 v = *(const bf16x8*)(part + (size_t)sl * Bdim * RANK + i8);
#pragma unroll
    for (int i = 0; i < 8; ++i) sum[i] += (float)v[i];
  }
  bf16x8 sv = *(const bf16x8*)(s + i8);
  bf16x8 o;
#pragma unroll
  for (int i = 0; i < 8; ++i) o[i] = (__bf16)(sum[i] * (float)sv[i]);
  *(bf16x8*)(proj + i8) = o;
}

// ---------------------------------------------------------------------------
// Out: out[m][n] = proj[m][:] @ V[n][:] + bias[n].  BM=BN=128, 4 waves (2x2).
//   A = proj bf16 [4096][256]; B = V fp32 [2048][256] staged w/ convert.
//   XCD-aware bijective swizzle of the 512 tiles (64 consecutive per XCD).
// ---------------------------------------------------------------------------
__global__ __launch_bounds__(256) void k_out(
    const __bf16* __restrict__ proj, const float* __restrict__ V,
    const float* __restrict__ bias, float* __restrict__ out) {
  constexpr int BM = 128, BN = 128, BK = 64;
  constexpr int Kt = RANK;
  __shared__ __align__(16) __bf16 As[BM * BK];
  __shared__ __align__(16) __bf16 Bs[BN * BK];
  const int t = threadIdx.x;
  // swizzle: lin -> (lin%8)*64 + lin/8 ; grid (32,16) = 512 tiles, 64/XCD
  const int lin = (int)(blockIdx.y * gridDim.x + blockIdx.x);
  const int swz = (lin & 7) * 64 + (lin >> 3);
  const int bm = (swz & 31) * BM;   // 32 m-tiles
  const int bn = (swz >> 5) * BN;   // 16 n-tiles
  const int w = t >> 6, l = t & 63;
  const int wr0 = (w >> 1) * 64;    // 2x2 waves
  const int wc0 = (w & 1) * 64;
  const int lrow = l & 15;
  const int lk   = l >> 4;
  f32x4 acc[4][4] = {};

  bf16x8 a_bf[4];
  float4 b_lo[4], b_hi[4];

  auto LOADA = [&](int k0) {
#pragma unroll
    for (int ci = 0; ci < 4; ++ci) {
      const int c = t + ci * 256;
      const int row = c >> 3, kc = c & 7;
      a_bf[ci] = *(const bf16x8*)(proj + (size_t)(bm + row) * Kt + k0 + kc * 8);
    }
  };
  auto LOADB = [&](int k0) {
#pragma unroll
    for (int ci = 0; ci < 4; ++ci) {
      const int c = t + ci * 256;
      const int row = c >> 3, kc = c & 7;
      const float* g = V + (size_t)(bn + row) * Kt + k0 + kc * 8;
      b_lo[ci] = *(const float4*)g;
      b_hi[ci] = *(const float4*)(g + 4);
    }
  };
  auto WRITEA = [&]() {
#pragma unroll
    for (int ci = 0; ci < 4; ++ci) {
      const int c = t + ci * 256;
      const int row = c >> 3, kc = c & 7;
      *(bf16x8*)((char*)As + row * 128 + ((kc ^ (row & 7)) * 16)) = a_bf[ci];
    }
  };
  auto WRITEB = [&]() {
#pragma unroll
    for (int ci = 0; ci < 4; ++ci) {
      const int c = t + ci * 256;
      const int row = c >> 3, kc = c & 7;
      bf16x8 v;
      v[0] = (__bf16)b_lo[ci].x; v[1] = (__bf16)b_lo[ci].y;
      v[2] = (__bf16)b_lo[ci].z; v[3] = (__bf16)b_lo[ci].w;
      v[4] = (__bf16)b_hi[ci].x; v[5] = (__bf16)b_hi[ci].y;
      v[6] = (__bf16)b_hi[ci].z; v[7] = (__bf16)b_hi[ci].w;
      *(bf16x8*)((char*)Bs + row * 128 + ((kc ^ (row & 7)) * 16)) = v;
    }
  };

  LOADA(0);
  LOADB(0);
  for (int k0 = 0; k0 < Kt; k0 += BK) {
    WRITEA();
    WRITEB();
    __syncthreads();
    if (k0 + BK < Kt) {
      LOADA(k0 + BK);
      LOADB(k0 + BK);
    }
#pragma unroll
    for (int kk = 0; kk < 2; ++kk) {
      bf16x8 af[4], bfr[4];
#pragma unroll
      for (int mf = 0; mf < 4; ++mf) {
        const int row = wr0 + mf * 16 + lrow;
        af[mf] = *(const bf16x8*)((const char*)As + row * 128 +
                                  (((kk * 4 + lk) ^ (row & 7)) * 16));
      }
#pragma unroll
      for (int nf = 0; nf < 4; ++nf) {
        const int row = wc0 + nf * 16 + lrow;
        bfr[nf] = *(const bf16x8*)((const char*)Bs + row * 128 +
                                   (((kk * 4 + lk) ^ (row & 7)) * 16));
      }
#pragma unroll
      for (int mf = 0; mf < 4; ++mf)
#pragma unroll
        for (int nf = 0; nf < 4; ++nf)
          acc[mf][nf] = __builtin_amdgcn_mfma_f32_16x16x32_bf16(
              af[mf], bfr[nf], acc[mf][nf], 0, 0, 0);
    }
    __syncthreads();
  }

#pragma unroll
  for (int mf = 0; mf < 4; ++mf) {
#pragma unroll
    for (int nf = 0; nf < 4; ++nf) {
#pragma unroll
      for (int r = 0; r < 4; ++r) {
        const int m = bm + wr0 + mf * 16 + lk * 4 + r;
        const int n = bn + wc0 + nf * 16 + lrow;
        out[(size_t)m * UNITS + n] = acc[mf][nf][r] + bias[n];
      }
    }
  }
}

}  // namespace

extern "C" void kernel_launch(void* const* d_in, const int* in_sizes, int n_in,
                              void* d_out, int out_size, void* d_ws, size_t ws_size,
                              hipStream_t stream) {
  const float* inputs  = (const float*)d_in[0];  // [4096, 2048]
  const float* context = (const float*)d_in[1];  // [4096, 512]
  const float* U       = (const float*)d_in[2];  // [2048, 256]
  const float* S       = (const float*)d_in[3];  // [256]
  const float* V       = (const float*)d_in[4];  // [2048, 256]
  const float* W       = (const float*)d_in[5];  // [512, 256]
  const float* Bc      = (const float*)d_in[6];  // [256]
  const float* bias    = (const float*)d_in[7];  // [2048]
  float* out = (float*)d_out;                    // [4096, 2048]

  char* ws = (char*)d_ws;
  __bf16* Ut   = (__bf16*)(ws);                  // 256x2048         (1 MB)
  __bf16* Wt   = (__bf16*)(ws + 1048576);        // 256x512          (256 KB)
  __bf16* proj = (__bf16*)(ws + 1310720);        // 4096x256         (2 MB)
  __bf16* sbuf = (__bf16*)(ws + 3407872);        // 4096x256         (2 MB)
  __bf16* part = (__bf16*)(ws + 5505024);        // SPLIT x4096x256  (8 MB)

  // 1) weight transpose+convert (Ut, Wt)
  k_prep<<<dim3(128, 2), 256, 0, stream>>>(U, W, Ut, Wt);

  // 2) merged: gate (y=0..1, writes s) + xU split-K partials (y=2..9)
  //    640 blocks, fully co-resident (3 blocks/CU LDS limit, 768 capacity)
  k_pg<<<dim3(Bdim / 64, 2 * SPLIT + 2), 256, 0, stream>>>(
      inputs, Ut, context, Wt, S, Bc, part, sbuf);

  // 3) proj = bf16( (sum partials) * s )   — pure-BW elementwise
  k_combine<<<dim3((Bdim * RANK) / (256 * 8)), 256, 0, stream>>>(part, sbuf, proj);

  // 4) out = proj @ V^T + bias   (V staged from fp32, XCD-swizzled tiles)
  k_out<<<dim3(Bdim / 128, UNITS / 128), 256, 0, stream>>>(proj, V, bias, out);
}